// Round 21
// baseline (949.295 us; speedup 1.0000x reference)
//
#include <hip/hip_runtime.h>
#include <math.h>

#define Bsz 32
#define Lseq 1024
#define CHUNK 64
#define NCHUNK 16

typedef __attribute__((ext_vector_type(8))) short s16x8v;
typedef __attribute__((ext_vector_type(4))) int   i32x4v;
typedef __attribute__((ext_vector_type(4))) float f32x4v;

__device__ __forceinline__ float fsig(float x) {
    return __builtin_amdgcn_rcpf(1.f + __expf(-x));
}
__device__ __forceinline__ float ftanh(float x) {
    float x2 = x * x;
    float poly = x * (1.f - 0.333333333f * x2 + 0.133333333f * x2 * x2);
    float big = 1.f - 2.f * __builtin_amdgcn_rcpf(1.f + __expf(2.f * x));
    return (x2 < 0.0025f) ? poly : big;
}
__device__ __forceinline__ float fsilu(float x) {
    return x * __builtin_amdgcn_rcpf(1.f + __expf(-x));
}
__device__ __forceinline__ unsigned bfr(float x) {   // f32 -> bf16 bits, RNE
    unsigned u = __float_as_uint(x);
    return (u + 0x7fffu + ((u >> 16) & 1u)) >> 16;
}
#define BFP(a, b) ( bfr(a) | (bfr(b) << 16) )

// ---------------- precompute ----------------
__global__ void k_pre(const float* w_proj, const float* b_proj, const float* w_inproj,
                      const float* A_log, const float* w_ih, const float* w_out,
                      const float* b_ih, const float* b_hh,
                      float* Ab, float* Minp, float* cinp,
                      unsigned short* M2p, float* c2) {
    int idx = blockIdx.x * 256 + threadIdx.x;
    if (idx < 4096) {
        Ab[idx] = -expf(A_log[idx]);
    } else if (idx < 4096 + 6144) {
        int j = idx - 4096; int o = j / 12; int i = j - o * 12;
        float s = 0.f;
        for (int k = 0; k < 128; ++k) s += w_inproj[o*128+k] * w_proj[k*12+i];
        Minp[j] = s;
    } else if (idx < 4096 + 6144 + 512) {
        int o = idx - (4096 + 6144);
        float s = 0.f;
        for (int k = 0; k < 128; ++k) s += w_inproj[o*128+k] * b_proj[k];
        cinp[o] = s;
    } else if (idx < 4096 + 6144 + 512 + 131072) {
        int j = idx - (4096 + 6144 + 512);
        int o = j >> 8; int dd = j & 255;
        float s = 0.f;
        for (int k = 0; k < 128; ++k) s += w_ih[o*128+k] * w_out[k*256+dd];
        int op = 4*(o & 127) + (o >> 7);      // gate-interleaved output index
        int col = op & 15, nt = op >> 4;
        int ks = dd >> 5, q = (dd >> 3) & 3, jj = dd & 7;
        M2p[(((nt*8 + ks)*64) + (q*16 + col))*8 + jj] = (unsigned short)bfr(s);
    } else if (idx < 4096 + 6144 + 512 + 131072 + 512) {
        int o = idx - (4096 + 6144 + 512 + 131072);
        c2[4*(o & 127) + (o >> 7)] = b_ih[o] + b_hh[o];
    }
}

// ---------------- k_front: fused inproj + depthwise conv + SiLU ----------------
__global__ void __launch_bounds__(256) k_front(const float* __restrict__ x,
                       const float* __restrict__ Minp, const float* __restrict__ cinp,
                       const float* __restrict__ conv_w, const float* __restrict__ conv_b,
                       float* __restrict__ uc, float* __restrict__ zb) {
    __shared__ float xs[67*12];
    int b = blockIdx.x >> 4;
    int c = blockIdx.x & 15;
    int d = threadIdx.x;
    int t0 = c * 64;
    for (int i = d; i < 67*12; i += 256) {
        int trel = i / 12;
        int t = t0 - 3 + trel;
        xs[i] = (t >= 0) ? x[(b*1024 + t)*12 + (i - trel*12)] : 0.f;
    }
    __syncthreads();
    float mu[12], mz[12];
#pragma unroll
    for (int i = 0; i < 12; ++i) { mu[i] = Minp[d*12 + i]; mz[i] = Minp[(256+d)*12 + i]; }
    float cu = cinp[d], cz = cinp[256 + d];
    float cw0 = conv_w[d*4+0], cw1 = conv_w[d*4+1], cw2 = conv_w[d*4+2], cw3 = conv_w[d*4+3];
    float cb = conv_b[d];
    float r0 = 0.f, r1 = 0.f, r2 = 0.f;
#pragma unroll
    for (int k = 0; k < 3; ++k) {
        int t = t0 - 3 + k;
        float v = 0.f;
        if (t >= 0) {
            const float* xr = &xs[k*12];
            v = cu;
#pragma unroll
            for (int i = 0; i < 12; ++i) v += mu[i]*xr[i];
        }
        r0 = r1; r1 = r2; r2 = v;
    }
    for (int t = t0; t < t0 + 64; ++t) {
        const float* xr = &xs[(t - t0 + 3)*12];
        float u = cu, z = cz;
#pragma unroll
        for (int i = 0; i < 12; ++i) { u += mu[i]*xr[i]; z += mz[i]*xr[i]; }
        float cv = cb + cw0*r0 + cw1*r1 + cw2*r2 + cw3*u;
        uc[(b*1024 + t)*256 + d] = fsilu(cv);
        zb[(b*1024 + t)*256 + d] = z;
        r0 = r1; r1 = r2; r2 = u;
    }
}

// ---------------- k3: xdbc + dt, 16 tokens per block (2048 blocks) ----------
__global__ void __launch_bounds__(256) k_xproj(const float* __restrict__ uc,
                        const float* __restrict__ w_xproj, const float* __restrict__ w_dt,
                        const float* __restrict__ b_dt,
                        float* __restrict__ dtb, float* __restrict__ Bm, float* __restrict__ Cm) {
    __shared__ float ut[16][257];
    __shared__ float xds[16][40];
    int tokbase = blockIdx.x * 16;
    int tid = threadIdx.x;
    for (int r = 0; r < 16; ++r) ut[r][tid] = uc[(size_t)(tokbase + r)*256 + tid];
    __syncthreads();
    int j = tid >> 2, q = tid & 3;
    if (j < 40) {
        const float* wr = w_xproj + j*256 + q*64;
        for (int r = 0; r < 16; ++r) {
            const float* uq = &ut[r][q*64];
            float s = 0.f;
#pragma unroll 8
            for (int k = 0; k < 64; ++k) s += wr[k] * uq[k];
            s += __shfl_xor(s, 1);
            s += __shfl_xor(s, 2);
            if (q == 0) {
                xds[r][j] = s;
                if (j >= 8 && j < 24)      Bm[(tokbase + r)*16 + (j - 8)]  = s;
                else if (j >= 24)          Cm[(tokbase + r)*16 + (j - 24)] = s;
            }
        }
    }
    __syncthreads();
    float wd0 = w_dt[tid*8+0], wd1 = w_dt[tid*8+1], wd2 = w_dt[tid*8+2], wd3 = w_dt[tid*8+3];
    float wd4 = w_dt[tid*8+4], wd5 = w_dt[tid*8+5], wd6 = w_dt[tid*8+6], wd7 = w_dt[tid*8+7];
    float bd = b_dt[tid];
    for (int r = 0; r < 16; ++r) {
        float s = bd;
        s += wd0*xds[r][0] + wd1*xds[r][1] + wd2*xds[r][2] + wd3*xds[r][3];
        s += wd4*xds[r][4] + wd5*xds[r][5] + wd6*xds[r][6] + wd7*xds[r][7];
        s = (s > 20.f) ? s : log1pf(expf(s));   // softplus
        dtb[(size_t)(tokbase + r)*256 + tid] = s;
    }
}

// ---------------- SSM chunked scan ----------------
__global__ void __launch_bounds__(256) k_ssm_p1(const float* __restrict__ dtb,
                        const float* __restrict__ uc, const float* __restrict__ Bm,
                        const float* __restrict__ Ab,
                        float* __restrict__ h0end, float* __restrict__ Ssum) {
    __shared__ float Bs[CHUNK*16];
    int b = blockIdx.x >> 4;
    int c = blockIdx.x & 15;
    int d = threadIdx.x;
    int t0 = c * CHUNK;
    {
        const float* src = Bm + (b*1024 + t0) * 16;
        for (int i = d; i < CHUNK*16; i += 256) Bs[i] = src[i];
    }
    __syncthreads();
    float a[16], h[16];
#pragma unroll
    for (int s = 0; s < 16; ++s) { a[s] = Ab[d*16+s]; h[s] = 0.f; }
    float S = 0.f;
    const float* dtp = dtb + (b*1024 + t0)*256 + d;
    const float* up  = uc  + (b*1024 + t0)*256 + d;
    float dtv = dtp[0], uv = up[0];
    for (int t = 0; t < CHUNK; ++t) {
        float dtn = 0.f, un = 0.f;
        if (t < CHUNK-1) { dtn = dtp[(t+1)*256]; un = up[(t+1)*256]; }
        float dtu = dtv * uv;
        S += dtv;
#pragma unroll
        for (int s = 0; s < 16; ++s) {
            float dA = __expf(dtv * a[s]);
            h[s] = h[s]*dA + dtu * Bs[t*16+s];
        }
        dtv = dtn; uv = un;
    }
    float* he = h0end + ((b*256 + d)*16 + c)*16;
#pragma unroll
    for (int s = 0; s < 16; ++s) he[s] = h[s];
    Ssum[(b*256 + d)*16 + c] = S;
}

__global__ void k_ssm_p2(const float* __restrict__ h0end, const float* __restrict__ Ssum,
                         const float* __restrict__ Ab, float* __restrict__ hinit) {
    int gid = blockIdx.x * 256 + threadIdx.x;   // 131072 = 32*256*16
    int s = gid & 15;
    int bd = gid >> 4;
    int d = bd & 255;
    float a = Ab[d*16 + s];
    float carry = 0.f;
    const float* he = h0end + bd * 256;
    float* hi = hinit + bd * 256;
    const float* Sp = Ssum + bd * 16;
    for (int c = 0; c < 16; ++c) {
        hi[c*16 + s] = carry;
        carry = he[c*16 + s] + __expf(a * Sp[c]) * carry;
    }
}

// phase 3: replay + fused yg -> bf16 (feeds MFMA k_xg)
__global__ void __launch_bounds__(256) k_ssm_p3(const float* __restrict__ dtb,
                        const float* __restrict__ uc, const float* __restrict__ zb,
                        const float* __restrict__ Bm, const float* __restrict__ Cm,
                        const float* __restrict__ Ab, const float* __restrict__ Dskip,
                        const float* __restrict__ hinit, unsigned short* __restrict__ ygb) {
    __shared__ float Bs[CHUNK*16];
    __shared__ float Cs[CHUNK*16];
    int b = blockIdx.x >> 4;
    int c = blockIdx.x & 15;
    int d = threadIdx.x;
    int t0 = c * CHUNK;
    {
        const float* srcB = Bm + (b*1024 + t0) * 16;
        const float* srcC = Cm + (b*1024 + t0) * 16;
        for (int i = d; i < CHUNK*16; i += 256) { Bs[i] = srcB[i]; Cs[i] = srcC[i]; }
    }
    __syncthreads();
    float a[16], h[16];
    const float* hi = hinit + ((b*256 + d)*16 + c)*16;
#pragma unroll
    for (int s = 0; s < 16; ++s) { a[s] = Ab[d*16+s]; h[s] = hi[s]; }
    float Dv = Dskip[d];
    const float* dtp = dtb + (b*1024 + t0)*256 + d;
    const float* up  = uc  + (b*1024 + t0)*256 + d;
    const float* zp  = zb  + (b*1024 + t0)*256 + d;
    unsigned short* yp = ygb + (b*1024 + t0)*256 + d;
    float dtv = dtp[0], uv = up[0], zv = zp[0];
    for (int t = 0; t < CHUNK; ++t) {
        float dtn = 0.f, un = 0.f, zn = 0.f;
        if (t < CHUNK-1) { dtn = dtp[(t+1)*256]; un = up[(t+1)*256]; zn = zp[(t+1)*256]; }
        float dtu = dtv * uv;
        float y = 0.f;
#pragma unroll
        for (int s = 0; s < 16; ++s) {
            float dA = __expf(dtv * a[s]);
            h[s] = h[s]*dA + dtu * Bs[t*16+s];
            y += h[s] * Cs[t*16+s];
        }
        yp[t*256] = (unsigned short)bfr((y + uv * Dv) * fsilu(zv));
        dtv = dtn; uv = un; zv = zn;
    }
}

// ---------------- k5: xg = yg @ M2 + c2 via bf16 MFMA ----------------
#define XGA(ks, Av) { \
    i32x4v ti = *(const i32x4v*)(ygb + (size_t)(tokbase + col)*256 + (ks)*32 + q*8); \
    Av = __builtin_bit_cast(s16x8v, ti); }
__global__ void __launch_bounds__(256) k_xg(const unsigned short* __restrict__ ygb,
                      const unsigned short* __restrict__ M2p, const float* __restrict__ c2,
                      float* __restrict__ xg) {
    int tid = threadIdx.x;
    int wv = tid >> 6;
    int l  = tid & 63;
    int col = l & 15;
    int q   = l >> 4;
    int tokbase = blockIdx.x * 64 + wv * 16;
    s16x8v A0, A1, A2, A3, A4, A5, A6, A7;
    XGA(0, A0) XGA(1, A1) XGA(2, A2) XGA(3, A3)
    XGA(4, A4) XGA(5, A5) XGA(6, A6) XGA(7, A7)
    for (int nt = 0; nt < 32; ++nt) {
        const i32x4v* bp = (const i32x4v*)(M2p + (size_t)(nt*8)*512 + l*8);
        f32x4v acc = (f32x4v){0.f, 0.f, 0.f, 0.f};
        s16x8v B0 = __builtin_bit_cast(s16x8v, bp[0*64]);
        s16x8v B1 = __builtin_bit_cast(s16x8v, bp[1*64]);
        s16x8v B2 = __builtin_bit_cast(s16x8v, bp[2*64]);
        s16x8v B3 = __builtin_bit_cast(s16x8v, bp[3*64]);
        s16x8v B4 = __builtin_bit_cast(s16x8v, bp[4*64]);
        s16x8v B5 = __builtin_bit_cast(s16x8v, bp[5*64]);
        s16x8v B6 = __builtin_bit_cast(s16x8v, bp[6*64]);
        s16x8v B7 = __builtin_bit_cast(s16x8v, bp[7*64]);
        acc = __builtin_amdgcn_mfma_f32_16x16x32_bf16(A0, B0, acc, 0, 0, 0);
        acc = __builtin_amdgcn_mfma_f32_16x16x32_bf16(A1, B1, acc, 0, 0, 0);
        acc = __builtin_amdgcn_mfma_f32_16x16x32_bf16(A2, B2, acc, 0, 0, 0);
        acc = __builtin_amdgcn_mfma_f32_16x16x32_bf16(A3, B3, acc, 0, 0, 0);
        acc = __builtin_amdgcn_mfma_f32_16x16x32_bf16(A4, B4, acc, 0, 0, 0);
        acc = __builtin_amdgcn_mfma_f32_16x16x32_bf16(A5, B5, acc, 0, 0, 0);
        acc = __builtin_amdgcn_mfma_f32_16x16x32_bf16(A6, B6, acc, 0, 0, 0);
        acc = __builtin_amdgcn_mfma_f32_16x16x32_bf16(A7, B7, acc, 0, 0, 0);
        float cc = c2[nt*16 + col];
#pragma unroll
        for (int r = 0; r < 4; ++r)
            xg[(size_t)(tokbase + q*4 + r)*512 + nt*16 + col] = acc[r] + cc;
    }
}

// ---------------- k6: LSTM via MFMA, broadcast-B, split accumulators ---------
// R20 (broadcast-B, in-lane gates, 0 bank conflicts) pinned at ~1410 cyc/step:
// neither gpre round-trip nor conflicts were critical. Remaining chain piece
// under our control: the 4-DEEP chained MFMA (~40-60 cyc dependent latency
// each). R16 "tested" acc-splitting but bundled it with the sched_barrier pin
// that caused its regression -- never cleanly measured. This round: 2
// independent accumulators per tile (chain depth 4 -> 2), combined AFTER the
// per-lane select as a scalar add (no vector-add latency on the path).
// Everything else byte-identical to R20.
#define BAR() asm volatile("s_waitcnt lgkmcnt(0)\ns_barrier" ::: "memory")
#define MKA(m, ks, Av) { \
    int rg = 16*(4*wv + (m)) + c16; \
    const float* wr0 = w_hh + ((rg & 3)*128 + (rg >> 2))*128 + (ks)*32 + q*8; \
    i32x4v ti; \
    ti.x = BFP(wr0[0], wr0[1]); ti.y = BFP(wr0[2], wr0[3]); \
    ti.z = BFP(wr0[4], wr0[5]); ti.w = BFP(wr0[6], wr0[7]); \
    Av = __builtin_bit_cast(s16x8v, ti); }
#define RDB(CUR, ks, Bv) { \
    i32x4v ti = *(const i32x4v*)(hl + (CUR)*128 + (ks)*32 + q*8); \
    Bv = __builtin_bit_cast(s16x8v, ti); }
#define TILE2(Aa, Ab_, Ac, Ad, ACCE, ACCO) { \
    ACCE = (f32x4v){0.f, 0.f, 0.f, 0.f}; \
    ACCO = (f32x4v){0.f, 0.f, 0.f, 0.f}; \
    ACCE = __builtin_amdgcn_mfma_f32_16x16x32_bf16(Aa,  B0, ACCE, 0, 0, 0); \
    ACCO = __builtin_amdgcn_mfma_f32_16x16x32_bf16(Ab_, B1, ACCO, 0, 0, 0); \
    ACCE = __builtin_amdgcn_mfma_f32_16x16x32_bf16(Ac,  B2, ACCE, 0, 0, 0); \
    ACCO = __builtin_amdgcn_mfma_f32_16x16x32_bf16(Ad,  B3, ACCO, 0, 0, 0); \
}
#define STEP2(CUR, NXT, XQ) { \
    s16x8v B0, B1, B2, B3; \
    RDB(CUR, 0, B0) RDB(CUR, 1, B1) RDB(CUR, 2, B2) RDB(CUR, 3, B3) \
    f32x4v e0, o0, e1, o1, e2, o2, e3, o3; \
    TILE2(A00, A01, A02, A03, e0, o0) \
    TILE2(A10, A11, A12, A13, e1, o1) \
    TILE2(A20, A21, A22, A23, e2, o2) \
    TILE2(A30, A31, A32, A33, e3, o3) \
    f32x4v te = (c16 < 8) ? ((c16 < 4) ? e0 : e1) : ((c16 < 12) ? e2 : e3); \
    f32x4v to = (c16 < 8) ? ((c16 < 4) ? o0 : o1) : ((c16 < 12) ? o2 : o3); \
    float pe = (rsel < 2) ? ((rsel < 1) ? te[0] : te[1]) : ((rsel < 3) ? te[2] : te[3]); \
    float po = (rsel < 2) ? ((rsel < 1) ? to[0] : to[1]) : ((rsel < 3) ? to[2] : to[3]); \
    float p = (pe + po) + (XQ); \
    float ye = aa * __builtin_amdgcn_rcpf(1.f + __expf(-sc * p)) + bb; \
    float p2 = p * p; \
    float ypo = p * (1.f - 0.333333333f*p2 + 0.133333333f*p2*p2); \
    float act = (gg2 && p2 < 0.0025f) ? ypo : ye; \
    float actf = __shfl(act, 1, 4); \
    float actg = __shfl(act, 2, 4); \
    float acto = __shfl(act, 3, 4); \
    if (rsel == 0) { \
        cst = actf * cst + act * actg; \
        hreg = acto * ftanh(cst); \
        hl[(NXT)*128 + uown] = (short)bfr(hreg); \
    } \
    BAR(); \
}

__global__ void __launch_bounds__(512)
k_lstm(const float* __restrict__ xg,
       const float* __restrict__ w_hh,
       const float* __restrict__ w_fc1, const float* __restrict__ b_fc1,
       const float* __restrict__ w_fc2, const float* __restrict__ b_fc2,
       float* __restrict__ out) {
    __shared__ __align__(16) short hl[2*128];      // double-buffered bf16 h
    __shared__ float fcbuf[128];
    __shared__ float relu[128];
    int b = blockIdx.x;
    int tid = threadIdx.x;
    int wv = tid >> 6;          // wave 0..7
    int l  = tid & 63;
    int c16 = l & 15;           // mfma column / A-row
    int q   = l >> 4;           // row-quad / k-group selector
    int rsel = c16 & 3;         // owned gate: 0=i 1=f 2=g 3=o
    int msel = c16 >> 2;        // owned tile
    int uown = 4*(4*wv + msel) + q;   // owned global unit (valid on rsel==0)
    bool gg2 = (rsel == 2);
    float sc = gg2 ? 2.f : 1.f;
    float aa = gg2 ? 2.f : 1.f;
    float bb = gg2 ? -1.f : 0.f;
    // A-fragments: 4 tiles x 4 k-steps, named (no arrays -> no scratch)
    s16x8v A00,A01,A02,A03, A10,A11,A12,A13, A20,A21,A22,A23, A30,A31,A32,A33;
    MKA(0,0,A00) MKA(0,1,A01) MKA(0,2,A02) MKA(0,3,A03)
    MKA(1,0,A10) MKA(1,1,A11) MKA(1,2,A12) MKA(1,3,A13)
    MKA(2,0,A20) MKA(2,1,A21) MKA(2,2,A22) MKA(2,3,A23)
    MKA(3,0,A30) MKA(3,1,A31) MKA(3,2,A32) MKA(3,3,A33)
    if (tid < 256) hl[tid] = 0;
    __syncthreads();
    float cst = 0.f, hreg = 0.f;
    // per-lane xq column: 4*unit + gate = 64wv + 16*msel + 4q + rsel
    int xoff = 64*wv + 16*msel + 4*q + rsel;
    const float* xqp = xg + (size_t)b * 1024 * 512 + xoff;
    float xqa = xqp[0];
    float xqb = xqp[512];
    for (int t = 0; t < 1024; t += 2) {
        float xa = xqa, xb = xqb;
        if (t + 2 < 1024) { xqa = xqp[(size_t)(t+2)*512]; xqb = xqp[(size_t)(t+3)*512]; }
        STEP2(0, 1, xa)
        STEP2(1, 0, xb)
    }
    // final h: owner lanes (rsel==0) hold hreg for unit uown
    if (rsel == 0) fcbuf[uown] = hreg;
    __syncthreads();
    // FC head
    if (tid < 128) {
        float s = b_fc1[tid];
        const float* wf = w_fc1 + tid*128;
#pragma unroll 4
        for (int k = 0; k < 128; ++k) s += wf[k] * fcbuf[k];
        relu[tid] = fmaxf(s, 0.f);
    }
    __syncthreads();
    if (tid < 5) {
        float s = b_fc2[tid];
        const float* wf = w_fc2 + tid*128;
        for (int k = 0; k < 128; ++k) s += wf[k] * relu[k];
        out[b*5 + tid] = s;
    }
}

// ---------------- launch ----------------
extern "C" void kernel_launch(void* const* d_in, const int* in_sizes, int n_in,
                              void* d_out, int out_size, void* d_ws, size_t ws_size,
                              hipStream_t stream) {
    const float* x        = (const float*)d_in[0];
    const float* w_proj   = (const float*)d_in[1];
    const float* b_proj   = (const float*)d_in[2];
    const float* w_inproj = (const float*)d_in[3];
    const float* conv_w   = (const float*)d_in[4];
    const float* conv_b   = (const float*)d_in[5];
    const float* w_xproj  = (const float*)d_in[6];
    const float* w_dt     = (const float*)d_in[7];
    const float* b_dt     = (const float*)d_in[8];
    const float* A_log    = (const float*)d_in[9];
    const float* Dskip    = (const float*)d_in[10];
    const float* w_out    = (const float*)d_in[11];
    const float* w_ih     = (const float*)d_in[12];
    const float* w_hh     = (const float*)d_in[13];
    const float* b_ih     = (const float*)d_in[14];
    const float* b_hh     = (const float*)d_in[15];
    const float* w_fc1    = (const float*)d_in[16];
    const float* b_fc1    = (const float*)d_in[17];
    const float* w_fc2    = (const float*)d_in[18];
    const float* b_fc2    = (const float*)d_in[19];
    float* outp = (float*)d_out;

    float* ws = (float*)d_ws;
    size_t off = 0;
    float* uc   = ws + off; off += 8388608;   // xg aliases uc+zb after p3
    float* zb   = ws + off; off += 8388608;
    float* dtb  = ws + off; off += 8388608;
    float* ygf  = ws + off; off += 8388608;   // ygb (bf16) lives here
    float* Bm   = ws + off; off += 524288;
    float* Cm   = ws + off; off += 524288;
    float* Ab   = ws + off; off += 4096;
    float* Minp = ws + off; off += 6144;
    float* cinp = ws + off; off += 512;
    float* M2f  = ws + off; off += 131072;    // M2p (bf16 packed) lives here
    float* c2   = ws + off; off += 512;
    float* h0end = ws + off; off += 2097152;
    float* Ssum  = ws + off; off += 131072;
    float* hinit = ws + off; off += 2097152;
    float* xg = uc;    // alias: spans uc+zb (16.7M floats), both dead after ssm_p3
    unsigned short* ygb = (unsigned short*)ygf;
    unsigned short* M2p = (unsigned short*)M2f;

    k_pre<<<556, 256, 0, stream>>>(w_proj, b_proj, w_inproj, A_log, w_ih, w_out,
                                   b_ih, b_hh, Ab, Minp, cinp, M2p, c2);
    k_front<<<512, 256, 0, stream>>>(x, Minp, cinp, conv_w, conv_b, uc, zb);
    k_xproj<<<2048, 256, 0, stream>>>(uc, w_xproj, w_dt, b_dt, dtb, Bm, Cm);
    k_ssm_p1<<<512, 256, 0, stream>>>(dtb, uc, Bm, Ab, h0end, Ssum);
    k_ssm_p2<<<512, 256, 0, stream>>>(h0end, Ssum, Ab, hinit);
    k_ssm_p3<<<512, 256, 0, stream>>>(dtb, uc, zb, Bm, Cm, Ab, Dskip, hinit, ygb);
    k_xg<<<512, 256, 0, stream>>>(ygb, M2p, c2, xg);
    k_lstm<<<32, 512, 0, stream>>>(xg, w_hh, w_fc1, b_fc1, w_fc2, b_fc2, outp);
}

// Round 22
// 908.713 us; speedup vs baseline: 1.0447x; 1.0447x over previous
//
#include <hip/hip_runtime.h>
#include <math.h>

#define Bsz 32
#define Lseq 1024
#define CHUNK 64
#define NCHUNK 16

typedef __attribute__((ext_vector_type(8))) short s16x8v;
typedef __attribute__((ext_vector_type(4))) int   i32x4v;
typedef __attribute__((ext_vector_type(4))) float f32x4v;

__device__ __forceinline__ float fsig(float x) {
    return __builtin_amdgcn_rcpf(1.f + __expf(-x));
}
__device__ __forceinline__ float ftanh(float x) {
    float x2 = x * x;
    float poly = x * (1.f - 0.333333333f * x2 + 0.133333333f * x2 * x2);
    float big = 1.f - 2.f * __builtin_amdgcn_rcpf(1.f + __expf(2.f * x));
    return (x2 < 0.0025f) ? poly : big;
}
__device__ __forceinline__ float fsilu(float x) {
    return x * __builtin_amdgcn_rcpf(1.f + __expf(-x));
}
__device__ __forceinline__ unsigned bfr(float x) {   // f32 -> bf16 bits, RNE
    unsigned u = __float_as_uint(x);
    return (u + 0x7fffu + ((u >> 16) & 1u)) >> 16;
}
#define BFP(a, b) ( bfr(a) | (bfr(b) << 16) )

// ---------------- precompute ----------------
__global__ void k_pre(const float* w_proj, const float* b_proj, const float* w_inproj,
                      const float* A_log, const float* w_ih, const float* w_out,
                      const float* b_ih, const float* b_hh,
                      float* Ab, float* Minp, float* cinp,
                      unsigned short* M2p, float* c2) {
    int idx = blockIdx.x * 256 + threadIdx.x;
    if (idx < 4096) {
        Ab[idx] = -expf(A_log[idx]);
    } else if (idx < 4096 + 6144) {
        int j = idx - 4096; int o = j / 12; int i = j - o * 12;
        float s = 0.f;
        for (int k = 0; k < 128; ++k) s += w_inproj[o*128+k] * w_proj[k*12+i];
        Minp[j] = s;
    } else if (idx < 4096 + 6144 + 512) {
        int o = idx - (4096 + 6144);
        float s = 0.f;
        for (int k = 0; k < 128; ++k) s += w_inproj[o*128+k] * b_proj[k];
        cinp[o] = s;
    } else if (idx < 4096 + 6144 + 512 + 131072) {
        int j = idx - (4096 + 6144 + 512);
        int o = j >> 8; int dd = j & 255;
        float s = 0.f;
        for (int k = 0; k < 128; ++k) s += w_ih[o*128+k] * w_out[k*256+dd];
        int op = 4*(o & 127) + (o >> 7);      // gate-interleaved output index
        int col = op & 15, nt = op >> 4;
        int ks = dd >> 5, q = (dd >> 3) & 3, jj = dd & 7;
        M2p[(((nt*8 + ks)*64) + (q*16 + col))*8 + jj] = (unsigned short)bfr(s);
    } else if (idx < 4096 + 6144 + 512 + 131072 + 512) {
        int o = idx - (4096 + 6144 + 512 + 131072);
        c2[4*(o & 127) + (o >> 7)] = b_ih[o] + b_hh[o];
    }
}

// ---------------- k_front: fused inproj + depthwise conv + SiLU ----------------
__global__ void __launch_bounds__(256) k_front(const float* __restrict__ x,
                       const float* __restrict__ Minp, const float* __restrict__ cinp,
                       const float* __restrict__ conv_w, const float* __restrict__ conv_b,
                       float* __restrict__ uc, float* __restrict__ zb) {
    __shared__ float xs[67*12];
    int b = blockIdx.x >> 4;
    int c = blockIdx.x & 15;
    int d = threadIdx.x;
    int t0 = c * 64;
    for (int i = d; i < 67*12; i += 256) {
        int trel = i / 12;
        int t = t0 - 3 + trel;
        xs[i] = (t >= 0) ? x[(b*1024 + t)*12 + (i - trel*12)] : 0.f;
    }
    __syncthreads();
    float mu[12], mz[12];
#pragma unroll
    for (int i = 0; i < 12; ++i) { mu[i] = Minp[d*12 + i]; mz[i] = Minp[(256+d)*12 + i]; }
    float cu = cinp[d], cz = cinp[256 + d];
    float cw0 = conv_w[d*4+0], cw1 = conv_w[d*4+1], cw2 = conv_w[d*4+2], cw3 = conv_w[d*4+3];
    float cb = conv_b[d];
    float r0 = 0.f, r1 = 0.f, r2 = 0.f;
#pragma unroll
    for (int k = 0; k < 3; ++k) {
        int t = t0 - 3 + k;
        float v = 0.f;
        if (t >= 0) {
            const float* xr = &xs[k*12];
            v = cu;
#pragma unroll
            for (int i = 0; i < 12; ++i) v += mu[i]*xr[i];
        }
        r0 = r1; r1 = r2; r2 = v;
    }
    for (int t = t0; t < t0 + 64; ++t) {
        const float* xr = &xs[(t - t0 + 3)*12];
        float u = cu, z = cz;
#pragma unroll
        for (int i = 0; i < 12; ++i) { u += mu[i]*xr[i]; z += mz[i]*xr[i]; }
        float cv = cb + cw0*r0 + cw1*r1 + cw2*r2 + cw3*u;
        uc[(b*1024 + t)*256 + d] = fsilu(cv);
        zb[(b*1024 + t)*256 + d] = z;
        r0 = r1; r1 = r2; r2 = u;
    }
}

// ---------------- k3: xdbc + dt, 16 tokens per block (2048 blocks) ----------
__global__ void __launch_bounds__(256) k_xproj(const float* __restrict__ uc,
                        const float* __restrict__ w_xproj, const float* __restrict__ w_dt,
                        const float* __restrict__ b_dt,
                        float* __restrict__ dtb, float* __restrict__ Bm, float* __restrict__ Cm) {
    __shared__ float ut[16][257];
    __shared__ float xds[16][40];
    int tokbase = blockIdx.x * 16;
    int tid = threadIdx.x;
    for (int r = 0; r < 16; ++r) ut[r][tid] = uc[(size_t)(tokbase + r)*256 + tid];
    __syncthreads();
    int j = tid >> 2, q = tid & 3;
    if (j < 40) {
        const float* wr = w_xproj + j*256 + q*64;
        for (int r = 0; r < 16; ++r) {
            const float* uq = &ut[r][q*64];
            float s = 0.f;
#pragma unroll 8
            for (int k = 0; k < 64; ++k) s += wr[k] * uq[k];
            s += __shfl_xor(s, 1);
            s += __shfl_xor(s, 2);
            if (q == 0) {
                xds[r][j] = s;
                if (j >= 8 && j < 24)      Bm[(tokbase + r)*16 + (j - 8)]  = s;
                else if (j >= 24)          Cm[(tokbase + r)*16 + (j - 24)] = s;
            }
        }
    }
    __syncthreads();
    float wd0 = w_dt[tid*8+0], wd1 = w_dt[tid*8+1], wd2 = w_dt[tid*8+2], wd3 = w_dt[tid*8+3];
    float wd4 = w_dt[tid*8+4], wd5 = w_dt[tid*8+5], wd6 = w_dt[tid*8+6], wd7 = w_dt[tid*8+7];
    float bd = b_dt[tid];
    for (int r = 0; r < 16; ++r) {
        float s = bd;
        s += wd0*xds[r][0] + wd1*xds[r][1] + wd2*xds[r][2] + wd3*xds[r][3];
        s += wd4*xds[r][4] + wd5*xds[r][5] + wd6*xds[r][6] + wd7*xds[r][7];
        s = (s > 20.f) ? s : log1pf(expf(s));   // softplus
        dtb[(size_t)(tokbase + r)*256 + tid] = s;
    }
}

// ---------------- SSM chunked scan ----------------
__global__ void __launch_bounds__(256) k_ssm_p1(const float* __restrict__ dtb,
                        const float* __restrict__ uc, const float* __restrict__ Bm,
                        const float* __restrict__ Ab,
                        float* __restrict__ h0end, float* __restrict__ Ssum) {
    __shared__ float Bs[CHUNK*16];
    int b = blockIdx.x >> 4;
    int c = blockIdx.x & 15;
    int d = threadIdx.x;
    int t0 = c * CHUNK;
    {
        const float* src = Bm + (b*1024 + t0) * 16;
        for (int i = d; i < CHUNK*16; i += 256) Bs[i] = src[i];
    }
    __syncthreads();
    float a[16], h[16];
#pragma unroll
    for (int s = 0; s < 16; ++s) { a[s] = Ab[d*16+s]; h[s] = 0.f; }
    float S = 0.f;
    const float* dtp = dtb + (b*1024 + t0)*256 + d;
    const float* up  = uc  + (b*1024 + t0)*256 + d;
    float dtv = dtp[0], uv = up[0];
    for (int t = 0; t < CHUNK; ++t) {
        float dtn = 0.f, un = 0.f;
        if (t < CHUNK-1) { dtn = dtp[(t+1)*256]; un = up[(t+1)*256]; }
        float dtu = dtv * uv;
        S += dtv;
#pragma unroll
        for (int s = 0; s < 16; ++s) {
            float dA = __expf(dtv * a[s]);
            h[s] = h[s]*dA + dtu * Bs[t*16+s];
        }
        dtv = dtn; uv = un;
    }
    float* he = h0end + ((b*256 + d)*16 + c)*16;
#pragma unroll
    for (int s = 0; s < 16; ++s) he[s] = h[s];
    Ssum[(b*256 + d)*16 + c] = S;
}

__global__ void k_ssm_p2(const float* __restrict__ h0end, const float* __restrict__ Ssum,
                         const float* __restrict__ Ab, float* __restrict__ hinit) {
    int gid = blockIdx.x * 256 + threadIdx.x;   // 131072 = 32*256*16
    int s = gid & 15;
    int bd = gid >> 4;
    int d = bd & 255;
    float a = Ab[d*16 + s];
    float carry = 0.f;
    const float* he = h0end + bd * 256;
    float* hi = hinit + bd * 256;
    const float* Sp = Ssum + bd * 16;
    for (int c = 0; c < 16; ++c) {
        hi[c*16 + s] = carry;
        carry = he[c*16 + s] + __expf(a * Sp[c]) * carry;
    }
}

// phase 3: replay + fused yg -> bf16 (feeds MFMA k_xg)
__global__ void __launch_bounds__(256) k_ssm_p3(const float* __restrict__ dtb,
                        const float* __restrict__ uc, const float* __restrict__ zb,
                        const float* __restrict__ Bm, const float* __restrict__ Cm,
                        const float* __restrict__ Ab, const float* __restrict__ Dskip,
                        const float* __restrict__ hinit, unsigned short* __restrict__ ygb) {
    __shared__ float Bs[CHUNK*16];
    __shared__ float Cs[CHUNK*16];
    int b = blockIdx.x >> 4;
    int c = blockIdx.x & 15;
    int d = threadIdx.x;
    int t0 = c * CHUNK;
    {
        const float* srcB = Bm + (b*1024 + t0) * 16;
        const float* srcC = Cm + (b*1024 + t0) * 16;
        for (int i = d; i < CHUNK*16; i += 256) { Bs[i] = srcB[i]; Cs[i] = srcC[i]; }
    }
    __syncthreads();
    float a[16], h[16];
    const float* hi = hinit + ((b*256 + d)*16 + c)*16;
#pragma unroll
    for (int s = 0; s < 16; ++s) { a[s] = Ab[d*16+s]; h[s] = hi[s]; }
    float Dv = Dskip[d];
    const float* dtp = dtb + (b*1024 + t0)*256 + d;
    const float* up  = uc  + (b*1024 + t0)*256 + d;
    const float* zp  = zb  + (b*1024 + t0)*256 + d;
    unsigned short* yp = ygb + (b*1024 + t0)*256 + d;
    float dtv = dtp[0], uv = up[0], zv = zp[0];
    for (int t = 0; t < CHUNK; ++t) {
        float dtn = 0.f, un = 0.f, zn = 0.f;
        if (t < CHUNK-1) { dtn = dtp[(t+1)*256]; un = up[(t+1)*256]; zn = zp[(t+1)*256]; }
        float dtu = dtv * uv;
        float y = 0.f;
#pragma unroll
        for (int s = 0; s < 16; ++s) {
            float dA = __expf(dtv * a[s]);
            h[s] = h[s]*dA + dtu * Bs[t*16+s];
            y += h[s] * Cs[t*16+s];
        }
        yp[t*256] = (unsigned short)bfr((y + uv * Dv) * fsilu(zv));
        dtv = dtn; uv = un; zv = zn;
    }
}

// ---------------- k5: xg = yg @ M2 + c2 via bf16 MFMA ----------------
#define XGA(ks, Av) { \
    i32x4v ti = *(const i32x4v*)(ygb + (size_t)(tokbase + col)*256 + (ks)*32 + q*8); \
    Av = __builtin_bit_cast(s16x8v, ti); }
__global__ void __launch_bounds__(256) k_xg(const unsigned short* __restrict__ ygb,
                      const unsigned short* __restrict__ M2p, const float* __restrict__ c2,
                      float* __restrict__ xg) {
    int tid = threadIdx.x;
    int wv = tid >> 6;
    int l  = tid & 63;
    int col = l & 15;
    int q   = l >> 4;
    int tokbase = blockIdx.x * 64 + wv * 16;
    s16x8v A0, A1, A2, A3, A4, A5, A6, A7;
    XGA(0, A0) XGA(1, A1) XGA(2, A2) XGA(3, A3)
    XGA(4, A4) XGA(5, A5) XGA(6, A6) XGA(7, A7)
    for (int nt = 0; nt < 32; ++nt) {
        const i32x4v* bp = (const i32x4v*)(M2p + (size_t)(nt*8)*512 + l*8);
        f32x4v acc = (f32x4v){0.f, 0.f, 0.f, 0.f};
        s16x8v B0 = __builtin_bit_cast(s16x8v, bp[0*64]);
        s16x8v B1 = __builtin_bit_cast(s16x8v, bp[1*64]);
        s16x8v B2 = __builtin_bit_cast(s16x8v, bp[2*64]);
        s16x8v B3 = __builtin_bit_cast(s16x8v, bp[3*64]);
        s16x8v B4 = __builtin_bit_cast(s16x8v, bp[4*64]);
        s16x8v B5 = __builtin_bit_cast(s16x8v, bp[5*64]);
        s16x8v B6 = __builtin_bit_cast(s16x8v, bp[6*64]);
        s16x8v B7 = __builtin_bit_cast(s16x8v, bp[7*64]);
        acc = __builtin_amdgcn_mfma_f32_16x16x32_bf16(A0, B0, acc, 0, 0, 0);
        acc = __builtin_amdgcn_mfma_f32_16x16x32_bf16(A1, B1, acc, 0, 0, 0);
        acc = __builtin_amdgcn_mfma_f32_16x16x32_bf16(A2, B2, acc, 0, 0, 0);
        acc = __builtin_amdgcn_mfma_f32_16x16x32_bf16(A3, B3, acc, 0, 0, 0);
        acc = __builtin_amdgcn_mfma_f32_16x16x32_bf16(A4, B4, acc, 0, 0, 0);
        acc = __builtin_amdgcn_mfma_f32_16x16x32_bf16(A5, B5, acc, 0, 0, 0);
        acc = __builtin_amdgcn_mfma_f32_16x16x32_bf16(A6, B6, acc, 0, 0, 0);
        acc = __builtin_amdgcn_mfma_f32_16x16x32_bf16(A7, B7, acc, 0, 0, 0);
        float cc = c2[nt*16 + col];
#pragma unroll
        for (int r = 0; r < 4; ++r)
            xg[(size_t)(tokbase + q*4 + r)*512 + nt*16 + col] = acc[r] + cc;
    }
}

// ---------------- k6: LSTM via MFMA, broadcast-B + in-lane gates (EXACT R20) --
// R21's accumulator split REGRESSED (603->643): the MFMA chain was not the
// binding constraint. This is the proven-best R20 form: broadcast-B (0 bank
// conflicts), in-lane gate ownership (no gpre round-trip), chained 4-MFMA
// tiles, one lgkm-fenced barrier per step.
#define BAR() asm volatile("s_waitcnt lgkmcnt(0)\ns_barrier" ::: "memory")
#define MKA(m, ks, Av) { \
    int rg = 16*(4*wv + (m)) + c16; \
    const float* wr0 = w_hh + ((rg & 3)*128 + (rg >> 2))*128 + (ks)*32 + q*8; \
    i32x4v ti; \
    ti.x = BFP(wr0[0], wr0[1]); ti.y = BFP(wr0[2], wr0[3]); \
    ti.z = BFP(wr0[4], wr0[5]); ti.w = BFP(wr0[6], wr0[7]); \
    Av = __builtin_bit_cast(s16x8v, ti); }
#define RDB(CUR, ks, Bv) { \
    i32x4v ti = *(const i32x4v*)(hl + (CUR)*128 + (ks)*32 + q*8); \
    Bv = __builtin_bit_cast(s16x8v, ti); }
#define TILE4(Aa, Ab_, Ac, Ad, ACC) { \
    ACC = (f32x4v){0.f, 0.f, 0.f, 0.f}; \
    ACC = __builtin_amdgcn_mfma_f32_16x16x32_bf16(Aa,  B0, ACC, 0, 0, 0); \
    ACC = __builtin_amdgcn_mfma_f32_16x16x32_bf16(Ab_, B1, ACC, 0, 0, 0); \
    ACC = __builtin_amdgcn_mfma_f32_16x16x32_bf16(Ac,  B2, ACC, 0, 0, 0); \
    ACC = __builtin_amdgcn_mfma_f32_16x16x32_bf16(Ad,  B3, ACC, 0, 0, 0); \
}
#define STEP2(CUR, NXT, XQ) { \
    s16x8v B0, B1, B2, B3; \
    RDB(CUR, 0, B0) RDB(CUR, 1, B1) RDB(CUR, 2, B2) RDB(CUR, 3, B3) \
    f32x4v ac0, ac1, ac2, ac3; \
    TILE4(A00, A01, A02, A03, ac0) \
    TILE4(A10, A11, A12, A13, ac1) \
    TILE4(A20, A21, A22, A23, ac2) \
    TILE4(A30, A31, A32, A33, ac3) \
    f32x4v tm = (c16 < 8) ? ((c16 < 4) ? ac0 : ac1) : ((c16 < 12) ? ac2 : ac3); \
    float pv = (rsel < 2) ? ((rsel < 1) ? tm[0] : tm[1]) : ((rsel < 3) ? tm[2] : tm[3]); \
    float p = pv + (XQ); \
    float ye = aa * __builtin_amdgcn_rcpf(1.f + __expf(-sc * p)) + bb; \
    float p2 = p * p; \
    float ypo = p * (1.f - 0.333333333f*p2 + 0.133333333f*p2*p2); \
    float act = (gg2 && p2 < 0.0025f) ? ypo : ye; \
    float actf = __shfl(act, 1, 4); \
    float actg = __shfl(act, 2, 4); \
    float acto = __shfl(act, 3, 4); \
    if (rsel == 0) { \
        cst = actf * cst + act * actg; \
        hreg = acto * ftanh(cst); \
        hl[(NXT)*128 + uown] = (short)bfr(hreg); \
    } \
    BAR(); \
}

__global__ void __launch_bounds__(512)
k_lstm(const float* __restrict__ xg,
       const float* __restrict__ w_hh,
       const float* __restrict__ w_fc1, const float* __restrict__ b_fc1,
       const float* __restrict__ w_fc2, const float* __restrict__ b_fc2,
       float* __restrict__ out) {
    __shared__ __align__(16) short hl[2*128];      // double-buffered bf16 h
    __shared__ float fcbuf[128];
    __shared__ float relu[128];
    int b = blockIdx.x;
    int tid = threadIdx.x;
    int wv = tid >> 6;          // wave 0..7
    int l  = tid & 63;
    int c16 = l & 15;           // mfma column / A-row
    int q   = l >> 4;           // row-quad / k-group selector
    int rsel = c16 & 3;         // owned gate: 0=i 1=f 2=g 3=o
    int msel = c16 >> 2;        // owned tile
    int uown = 4*(4*wv + msel) + q;   // owned global unit (valid on rsel==0)
    bool gg2 = (rsel == 2);
    float sc = gg2 ? 2.f : 1.f;
    float aa = gg2 ? 2.f : 1.f;
    float bb = gg2 ? -1.f : 0.f;
    // A-fragments: 4 tiles x 4 k-steps, named (no arrays -> no scratch)
    s16x8v A00,A01,A02,A03, A10,A11,A12,A13, A20,A21,A22,A23, A30,A31,A32,A33;
    MKA(0,0,A00) MKA(0,1,A01) MKA(0,2,A02) MKA(0,3,A03)
    MKA(1,0,A10) MKA(1,1,A11) MKA(1,2,A12) MKA(1,3,A13)
    MKA(2,0,A20) MKA(2,1,A21) MKA(2,2,A22) MKA(2,3,A23)
    MKA(3,0,A30) MKA(3,1,A31) MKA(3,2,A32) MKA(3,3,A33)
    if (tid < 256) hl[tid] = 0;
    __syncthreads();
    float cst = 0.f, hreg = 0.f;
    // per-lane xq column: 4*unit + gate = 64wv + 16*msel + 4q + rsel
    int xoff = 64*wv + 16*msel + 4*q + rsel;
    const float* xqp = xg + (size_t)b * 1024 * 512 + xoff;
    float xqa = xqp[0];
    float xqb = xqp[512];
    for (int t = 0; t < 1024; t += 2) {
        float xa = xqa, xb = xqb;
        if (t + 2 < 1024) { xqa = xqp[(size_t)(t+2)*512]; xqb = xqp[(size_t)(t+3)*512]; }
        STEP2(0, 1, xa)
        STEP2(1, 0, xb)
    }
    // final h: owner lanes (rsel==0) hold hreg for unit uown
    if (rsel == 0) fcbuf[uown] = hreg;
    __syncthreads();
    // FC head
    if (tid < 128) {
        float s = b_fc1[tid];
        const float* wf = w_fc1 + tid*128;
#pragma unroll 4
        for (int k = 0; k < 128; ++k) s += wf[k] * fcbuf[k];
        relu[tid] = fmaxf(s, 0.f);
    }
    __syncthreads();
    if (tid < 5) {
        float s = b_fc2[tid];
        const float* wf = w_fc2 + tid*128;
        for (int k = 0; k < 128; ++k) s += wf[k] * relu[k];
        out[b*5 + tid] = s;
    }
}

// ---------------- launch ----------------
extern "C" void kernel_launch(void* const* d_in, const int* in_sizes, int n_in,
                              void* d_out, int out_size, void* d_ws, size_t ws_size,
                              hipStream_t stream) {
    const float* x        = (const float*)d_in[0];
    const float* w_proj   = (const float*)d_in[1];
    const float* b_proj   = (const float*)d_in[2];
    const float* w_inproj = (const float*)d_in[3];
    const float* conv_w   = (const float*)d_in[4];
    const float* conv_b   = (const float*)d_in[5];
    const float* w_xproj  = (const float*)d_in[6];
    const float* w_dt     = (const float*)d_in[7];
    const float* b_dt     = (const float*)d_in[8];
    const float* A_log    = (const float*)d_in[9];
    const float* Dskip    = (const float*)d_in[10];
    const float* w_out    = (const float*)d_in[11];
    const float* w_ih     = (const float*)d_in[12];
    const float* w_hh     = (const float*)d_in[13];
    const float* b_ih     = (const float*)d_in[14];
    const float* b_hh     = (const float*)d_in[15];
    const float* w_fc1    = (const float*)d_in[16];
    const float* b_fc1    = (const float*)d_in[17];
    const float* w_fc2    = (const float*)d_in[18];
    const float* b_fc2    = (const float*)d_in[19];
    float* outp = (float*)d_out;

    float* ws = (float*)d_ws;
    size_t off = 0;
    float* uc   = ws + off; off += 8388608;   // xg aliases uc+zb after p3
    float* zb   = ws + off; off += 8388608;
    float* dtb  = ws + off; off += 8388608;
    float* ygf  = ws + off; off += 8388608;   // ygb (bf16) lives here
    float* Bm   = ws + off; off += 524288;
    float* Cm   = ws + off; off += 524288;
    float* Ab   = ws + off; off += 4096;
    float* Minp = ws + off; off += 6144;
    float* cinp = ws + off; off += 512;
    float* M2f  = ws + off; off += 131072;    // M2p (bf16 packed) lives here
    float* c2   = ws + off; off += 512;
    float* h0end = ws + off; off += 2097152;
    float* Ssum  = ws + off; off += 131072;
    float* hinit = ws + off; off += 2097152;
    float* xg = uc;    // alias: spans uc+zb (16.7M floats), both dead after ssm_p3
    unsigned short* ygb = (unsigned short*)ygf;
    unsigned short* M2p = (unsigned short*)M2f;

    k_pre<<<556, 256, 0, stream>>>(w_proj, b_proj, w_inproj, A_log, w_ih, w_out,
                                   b_ih, b_hh, Ab, Minp, cinp, M2p, c2);
    k_front<<<512, 256, 0, stream>>>(x, Minp, cinp, conv_w, conv_b, uc, zb);
    k_xproj<<<2048, 256, 0, stream>>>(uc, w_xproj, w_dt, b_dt, dtb, Bm, Cm);
    k_ssm_p1<<<512, 256, 0, stream>>>(dtb, uc, Bm, Ab, h0end, Ssum);
    k_ssm_p2<<<512, 256, 0, stream>>>(h0end, Ssum, Ab, hinit);
    k_ssm_p3<<<512, 256, 0, stream>>>(dtb, uc, zb, Bm, Cm, Ab, Dskip, hinit, ygb);
    k_xg<<<512, 256, 0, stream>>>(ygb, M2p, c2, xg);
    k_lstm<<<32, 512, 0, stream>>>(xg, w_hh, w_fc1, b_fc1, w_fc2, b_fc2, outp);
}